// Round 1
// baseline (555.335 us; speedup 1.0000x reference)
//
#include <hip/hip_runtime.h>

#define Bn   64
#define Tn   128
#define NKn  200
#define En   64
#define Gn   256
#define Ln   40

__device__ __forceinline__ float sigm_f(float x){ return 1.0f/(1.0f+__expf(-x)); }
__device__ __forceinline__ float tanh_f(float x){ float e=__expf(2.0f*x); return 1.0f-2.0f/(e+1.0f); }

// ---------------- embedding gather-sum: out[row][64] = sum_t emb[tok[row][t]] ----------------
__global__ __launch_bounds__(256) void embed_sum(const int* __restrict__ toks,
                                                 const float* __restrict__ emb,
                                                 float* __restrict__ out){
  int tid = threadIdx.x;
  int row = blockIdx.x*16 + (tid>>4);
  int e4  = tid & 15;
  const int* tr = toks + row*Ln;
  float4 acc = {0.f,0.f,0.f,0.f};
  for (int t=0;t<Ln;t++){
    int tok = tr[t];
    float4 v = ((const float4*)emb)[tok*16 + e4];
    acc.x+=v.x; acc.y+=v.y; acc.z+=v.z; acc.w+=v.w;
  }
  ((float4*)out)[row*16+e4] = acc;
}

// ---------------- out[m][g] = x[m]·W[g] + b1[g] + b2[g]   (M rows, G=256, J=64) -------------
__global__ __launch_bounds__(256) void gemm_xw(const float* __restrict__ x,
                                               const float* __restrict__ W,
                                               const float* __restrict__ b1,
                                               const float* __restrict__ b2,
                                               float* __restrict__ out){
  __shared__ __attribute__((aligned(16))) float xs[32*64];
  int tid = threadIdx.x;
  int m0  = blockIdx.x*32;
  for (int q=0;q<8;q++){ int i=q*256+tid; xs[i] = x[m0*64 + i]; }
  float4 w[16];
  const float4* W4 = (const float4*)(W + tid*64);
  #pragma unroll
  for (int j=0;j<16;j++) w[j]=W4[j];
  float bias = b1[tid]+b2[tid];
  __syncthreads();
  for (int rr=0;rr<32;rr++){
    const float4* h4 = (const float4*)(xs + rr*64);
    float acc = bias;
    #pragma unroll
    for (int j=0;j<16;j++){
      float4 hv=h4[j];
      acc += w[j].x*hv.x + w[j].y*hv.y + w[j].z*hv.z + w[j].w*hv.w;
    }
    out[(m0+rr)*256 + tid] = acc;
  }
}

// ---------------- BiLSTM recurrence: 128 blocks = 64 batches x 2 directions ----------------
__global__ __launch_bounds__(256) void lstm_seq(const float* __restrict__ xg_f,
                                                const float* __restrict__ xg_b,
                                                const float* __restrict__ Whh_f,
                                                const float* __restrict__ Whh_b,
                                                float* __restrict__ hf,
                                                float* __restrict__ hb){
  int tid = threadIdx.x;
  int dir = blockIdx.x >> 6;
  int b   = blockIdx.x & 63;
  const float* xg  = dir? xg_b  : xg_f;
  const float* Whh = dir? Whh_b : Whh_f;
  float* out       = dir? hb    : hf;
  __shared__ __attribute__((aligned(16))) float h_s[64];
  __shared__ float c_s[64];
  __shared__ float z_s[256];
  float4 w[16];
  const float4* W4 = (const float4*)(Whh + tid*64);
  #pragma unroll
  for (int j=0;j<16;j++) w[j]=W4[j];
  if (tid<64){ h_s[tid]=0.f; c_s[tid]=0.f; }
  __syncthreads();
  for (int s=0;s<NKn;s++){
    int t = dir ? (NKn-1-s) : s;
    float acc = xg[(b*NKn+t)*256 + tid];
    const float4* h4 = (const float4*)h_s;
    #pragma unroll
    for (int j=0;j<16;j++){
      float4 hv=h4[j];
      acc += w[j].x*hv.x + w[j].y*hv.y + w[j].z*hv.z + w[j].w*hv.w;
    }
    z_s[tid]=acc;
    __syncthreads();                 // all h_s reads done; z complete
    if (tid<64){
      float iv = sigm_f(z_s[tid]);
      float fv = sigm_f(z_s[64+tid]);
      float gv = tanh_f(z_s[128+tid]);
      float ov = sigm_f(z_s[192+tid]);
      float c  = fv*c_s[tid] + iv*gv;
      c_s[tid]=c;
      float h  = ov*tanh_f(c);
      h_s[tid]=h;
      out[(b*NKn+t)*64 + tid] = h;
    }
    __syncthreads();                 // h_s updated before next step reads
  }
}

// ---------------- sup_emb = hf + hb + sup_enc; sn = ||sup_emb|| ----------------
__global__ __launch_bounds__(256) void combine(const float* __restrict__ hf,
                                               const float* __restrict__ hb,
                                               const float* __restrict__ sup_enc,
                                               float* __restrict__ semb,
                                               float* __restrict__ sn){
  int lane = threadIdx.x&63; int wv = threadIdx.x>>6;
  int m = blockIdx.x*4+wv;
  float v = hf[m*64+lane] + hb[m*64+lane] + sup_enc[m*64+lane];
  semb[m*64+lane]=v;
  float s=v*v;
  #pragma unroll
  for (int o=32;o>0;o>>=1) s += __shfl_xor(s,o,64);
  if (lane==0) sn[m]=sqrtf(s);
}

// ---------------- cell step: h_used = h_in + r; (h_next,c) = LSTMCell; h_next += x --------
__global__ __launch_bounds__(256) void cell_step(const float* __restrict__ h_in,
                                                 const float* __restrict__ r_in,
                                                 const float* __restrict__ zx,
                                                 const float* __restrict__ Whh,
                                                 const float* __restrict__ x,
                                                 float* __restrict__ c_io,
                                                 float* __restrict__ h_used,
                                                 float* __restrict__ h_next){
  __shared__ __attribute__((aligned(16))) float hu_s[16*64];
  __shared__ float z_s[16*256];
  int tid = threadIdx.x;
  int m0  = blockIdx.x*16;
  for (int q=0;q<4;q++){
    int i=q*256+tid;
    float hu = h_in[m0*64+i] + r_in[m0*64+i];
    hu_s[i]=hu;
    h_used[m0*64+i]=hu;
  }
  float4 w[16];
  const float4* W4 = (const float4*)(Whh + tid*64);
  #pragma unroll
  for (int j=0;j<16;j++) w[j]=W4[j];
  __syncthreads();
  for (int rr=0; rr<16; rr++){
    float acc = zx[(m0+rr)*256+tid];
    const float4* h4 = (const float4*)(hu_s + rr*64);
    #pragma unroll
    for (int j=0;j<16;j++){
      float4 hv=h4[j];
      acc += w[j].x*hv.x + w[j].y*hv.y + w[j].z*hv.z + w[j].w*hv.w;
    }
    z_s[rr*256+tid]=acc;
  }
  __syncthreads();
  int e  = tid&63;
  int r0 = tid>>6;
  for (int q=0;q<4;q++){
    int rr = q*4 + r0;
    int m  = m0+rr;
    float iv = sigm_f(z_s[rr*256+e]);
    float fv = sigm_f(z_s[rr*256+64+e]);
    float gv = tanh_f(z_s[rr*256+128+e]);
    float ov = sigm_f(z_s[rr*256+192+e]);
    float c  = fv*c_io[m*64+e] + iv*gv;
    c_io[m*64+e]=c;
    h_next[m*64+e] = ov*tanh_f(c) + x[m*64+e];
  }
}

// ---------------- attention: scores -> softmax -> r   (16 targets / block) ----------------
__global__ __launch_bounds__(256) void attn_step(const float* __restrict__ h_used,
                                                 const float* __restrict__ semb,
                                                 float* __restrict__ r_out){
  __shared__ float ss[200*65];                                   // 52 KB, stride 65
  __shared__ __attribute__((aligned(16))) float hu_s[16*64];     // 4 KB
  __shared__ __attribute__((aligned(16))) float str[200*20];     // 16 KB, stride 20
  int tid = threadIdx.x;
  int b   = blockIdx.x>>3;
  int t0  = (blockIdx.x&7)*16;
  for (int q=0;q<50;q++){
    int i=q*256+tid; int j=i>>6, e=i&63;
    ss[j*65+e] = semb[(b*NKn+j)*64+e];
  }
  for (int q=0;q<4;q++){
    int i=q*256+tid;
    hu_s[i] = h_used[(b*Tn+t0)*64 + i];
  }
  __syncthreads();
  int j = tid;
  float rw[64];
  if (j<200){
    #pragma unroll
    for (int e2=0;e2<64;e2++) rw[e2]=ss[j*65+e2];
    for (int t=0;t<16;t++){
      const float4* h4 = (const float4*)(hu_s + t*64);
      float acc=0.f;
      #pragma unroll
      for (int jj=0;jj<16;jj++){
        float4 hv=h4[jj];
        acc += rw[4*jj]*hv.x + rw[4*jj+1]*hv.y + rw[4*jj+2]*hv.z + rw[4*jj+3]*hv.w;
      }
      str[j*20+t]=acc;
    }
  }
  __syncthreads();
  int lane = tid&63; int wv = tid>>6;
  for (int tq=0; tq<4; tq++){
    int t = wv*4+tq;
    float mx=-1e30f;
    for (int q=0;q<4;q++){ int jj=q*64+lane; if (jj<200) mx=fmaxf(mx, str[jj*20+t]); }
    #pragma unroll
    for (int o=32;o>0;o>>=1) mx = fmaxf(mx, __shfl_xor(mx,o,64));
    float sm=0.f;
    for (int q=0;q<4;q++){ int jj=q*64+lane; if (jj<200){ float ev=__expf(str[jj*20+t]-mx); str[jj*20+t]=ev; sm+=ev; } }
    #pragma unroll
    for (int o=32;o>0;o>>=1) sm += __shfl_xor(sm,o,64);
    float inv = 1.0f/sm;
    for (int q=0;q<4;q++){ int jj=q*64+lane; if (jj<200) str[jj*20+t]*=inv; }
  }
  __syncthreads();
  int e = tid&63; int ch = tid>>6;
  float a0=0.f,a1=0.f,a2=0.f,a3=0.f;
  for (int jj=0;jj<200;jj++){
    float v = ss[jj*65+e];
    float4 at = *(const float4*)(str + jj*20 + ch*4);
    a0 += at.x*v; a1 += at.y*v; a2 += at.z*v; a3 += at.w*v;
  }
  int mb = b*Tn + t0 + ch*4;
  r_out[(mb+0)*64+e]=a0;
  r_out[(mb+1)*64+e]=a1;
  r_out[(mb+2)*64+e]=a2;
  r_out[(mb+3)*64+e]=a3;
}

// ---------------- row norms of h_final ----------------
__global__ __launch_bounds__(256) void norm_rows(const float* __restrict__ h,
                                                 float* __restrict__ tn){
  int lane = threadIdx.x&63; int wv=threadIdx.x>>6;
  int m = blockIdx.x*4+wv;
  float v = h[m*64+lane];
  float s = v*v;
  #pragma unroll
  for (int o=32;o>0;o>>=1) s += __shfl_xor(s,o,64);
  if (lane==0) tn[m]=sqrtf(s);
}

// ---------------- final cosine-sim softmax -> d_out ----------------
__global__ __launch_bounds__(256) void final_attn(const float* __restrict__ h_fin,
                                                  const float* __restrict__ semb,
                                                  const float* __restrict__ tn,
                                                  const float* __restrict__ sn,
                                                  float* __restrict__ out){
  __shared__ float ss[200*65];
  __shared__ __attribute__((aligned(16))) float hu_s[16*64];
  __shared__ float str[200*20];
  __shared__ float tn_s[16];
  int tid = threadIdx.x;
  int b   = blockIdx.x>>3;
  int t0  = (blockIdx.x&7)*16;
  for (int q=0;q<50;q++){
    int i=q*256+tid; int j=i>>6, e=i&63;
    ss[j*65+e] = semb[(b*NKn+j)*64+e];
  }
  for (int q=0;q<4;q++){
    int i=q*256+tid;
    hu_s[i] = h_fin[(b*Tn+t0)*64 + i];
  }
  if (tid<16) tn_s[tid] = tn[b*Tn+t0+tid];
  __syncthreads();
  int j = tid;
  if (j<200){
    float rw[64];
    #pragma unroll
    for (int e2=0;e2<64;e2++) rw[e2]=ss[j*65+e2];
    float snj = sn[b*NKn+j];
    for (int t=0;t<16;t++){
      const float4* h4 = (const float4*)(hu_s + t*64);
      float acc=0.f;
      #pragma unroll
      for (int jj=0;jj<16;jj++){
        float4 hv=h4[jj];
        acc += rw[4*jj]*hv.x + rw[4*jj+1]*hv.y + rw[4*jj+2]*hv.z + rw[4*jj+3]*hv.w;
      }
      float denom = fmaxf(tn_s[t]*snj, 1e-8f);
      str[j*20+t]=acc/denom;
    }
  }
  __syncthreads();
  int lane = tid&63; int wv = tid>>6;
  for (int tq=0; tq<4; tq++){
    int t = wv*4+tq;
    float mx=-1e30f;
    for (int q=0;q<4;q++){ int jj=q*64+lane; if (jj<200) mx=fmaxf(mx, str[jj*20+t]); }
    #pragma unroll
    for (int o=32;o>0;o>>=1) mx = fmaxf(mx, __shfl_xor(mx,o,64));
    float sm=0.f;
    for (int q=0;q<4;q++){ int jj=q*64+lane; if (jj<200){ float ev=__expf(str[jj*20+t]-mx); str[jj*20+t]=ev; sm+=ev; } }
    #pragma unroll
    for (int o=32;o>0;o>>=1) sm += __shfl_xor(sm,o,64);
    float inv = 1.0f/sm;
    for (int q=0;q<4;q++){
      int jj=q*64+lane;
      if (jj<200) out[(size_t)(b*Tn+t0+t)*NKn + jj] = str[jj*20+t]*inv;
    }
  }
}

extern "C" void kernel_launch(void* const* d_in, const int* in_sizes, int n_in,
                              void* d_out, int out_size, void* d_ws, size_t ws_size,
                              hipStream_t stream) {
  (void)in_sizes; (void)n_in; (void)out_size; (void)ws_size;
  const int*   sup_toks = (const int*)d_in[0];
  const int*   tgt_toks = (const int*)d_in[1];
  const float* emb      = (const float*)d_in[2];
  const float* f_Wih    = (const float*)d_in[3];
  const float* f_Whh    = (const float*)d_in[4];
  const float* f_bih    = (const float*)d_in[5];
  const float* f_bhh    = (const float*)d_in[6];
  const float* gf_Wih   = (const float*)d_in[7];
  const float* gf_Whh   = (const float*)d_in[8];
  const float* gf_bih   = (const float*)d_in[9];
  const float* gf_bhh   = (const float*)d_in[10];
  const float* gb_Wih   = (const float*)d_in[11];
  const float* gb_Whh   = (const float*)d_in[12];
  const float* gb_bih   = (const float*)d_in[13];
  const float* gb_bhh   = (const float*)d_in[14];

  float* ws = (float*)d_ws;
  // workspace layout (floats); total 9,556,480 fl = 38.2 MB
  float* sup_enc = ws;                         // 819200
  float* tgt_enc = sup_enc + 819200;           // 524288
  float* bufA    = tgt_enc + 524288;           // 3276800 : xg_f, later zx
  float* bufB    = bufA    + 3276800;          // 3276800 : xg_b, later h0/h1/c/r/h_used
  float* semb    = bufB    + 3276800;          // 819200  : hf, then sup_emb
  float* hb      = semb    + 819200;           // 819200
  float* sn      = hb      + 819200;           // 12800
  float* tn      = sn      + 12800;            // 8192

  float* xg_f = bufA;
  float* xg_b = bufB;

  // phase A: embedding sums
  embed_sum<<<800,256,0,stream>>>(sup_toks, emb, sup_enc);   // 12800 rows
  embed_sum<<<512,256,0,stream>>>(tgt_toks, emb, tgt_enc);   // 8192 rows

  // phase B: BiLSTM
  gemm_xw<<<400,256,0,stream>>>(sup_enc, gf_Wih, gf_bih, gf_bhh, xg_f);
  gemm_xw<<<400,256,0,stream>>>(sup_enc, gb_Wih, gb_bih, gb_bhh, xg_b);
  lstm_seq<<<128,256,0,stream>>>(xg_f, xg_b, gf_Whh, gb_Whh, semb /*hf*/, hb);
  combine<<<3200,256,0,stream>>>(semb, hb, sup_enc, semb, sn);

  // phase C: K=5 attention-LSTM iterations (bufA,bufB now dead -> reuse)
  float* zx     = bufA;                 // 2097152
  float* h0     = bufB;                 // 524288
  float* h1     = h0 + 524288;
  float* cbuf   = h1 + 524288;
  float* rbuf   = cbuf + 524288;
  float* h_used = rbuf + 524288;

  gemm_xw<<<256,256,0,stream>>>(tgt_enc, f_Wih, f_bih, f_bhh, zx);
  hipMemsetAsync(h0, 0, (size_t)4*524288*sizeof(float), stream);  // h0,h1,c,r = 0

  for (int k=0;k<5;k++){
    float* hin  = (k&1)? h1 : h0;
    float* hout = (k&1)? h0 : h1;
    cell_step<<<512,256,0,stream>>>(hin, rbuf, zx, f_Whh, tgt_enc, cbuf, h_used, hout);
    if (k<4) attn_step<<<512,256,0,stream>>>(h_used, semb, rbuf);
  }
  // final h is h1 (k=4: hin=h0 -> hout=h1)
  norm_rows<<<2048,256,0,stream>>>(h1, tn);
  final_attn<<<512,256,0,stream>>>(h1, semb, tn, sn, (float*)d_out);
}

// Round 2
// 502.090 us; speedup vs baseline: 1.1060x; 1.1060x over previous
//
#include <hip/hip_runtime.h>

#define Bn   64
#define Tn   128
#define NKn  200
#define En   64
#define Ln   40

__device__ __forceinline__ float sigm_f(float x){ return 1.0f/(1.0f+__expf(-x)); }
__device__ __forceinline__ float tanh_f(float x){ float e=__expf(2.0f*x); return 1.0f-2.0f/(e+1.0f); }
// broadcast lane `ln` of v to all lanes via v_readlane (VALU pipe, no LDS traffic)
__device__ __forceinline__ float rdl(float v, int ln){
  return __uint_as_float(__builtin_amdgcn_readlane(__float_as_uint(v), (unsigned)ln));
}

// ---------------- embedding gather-sum: out[row][64] = sum_t emb[tok[row][t]] ----------------
__global__ __launch_bounds__(256) void embed_sum(const int* __restrict__ toks,
                                                 const float* __restrict__ emb,
                                                 float* __restrict__ out){
  int tid = threadIdx.x;
  int row = blockIdx.x*16 + (tid>>4);
  int e4  = tid & 15;
  const int* tr = toks + (size_t)row*Ln;
  float4 acc = {0.f,0.f,0.f,0.f};
  for (int t=0;t<Ln;t++){
    int tok = tr[t];
    float4 v = ((const float4*)emb)[(size_t)tok*16 + e4];
    acc.x+=v.x; acc.y+=v.y; acc.z+=v.z; acc.w+=v.w;
  }
  ((float4*)out)[(size_t)row*16+e4] = acc;
}

// ---------------- out[m][g] = x[m]·W[g] + b1[g] + b2[g]  (16 rows/block, readlane bcast) ----
__global__ __launch_bounds__(256,1) void gemm_xw(const float* __restrict__ x,
                                                 const float* __restrict__ W,
                                                 const float* __restrict__ b1,
                                                 const float* __restrict__ b2,
                                                 float* __restrict__ out){
  int tid=threadIdx.x, l=tid&63, w=tid>>6;
  int g = w*64+l;
  int m0 = blockIdx.x*16;
  float wr[64];
  const float4* W4=(const float4*)(W + (size_t)g*64);
  #pragma unroll
  for(int q=0;q<16;q++){ float4 v=W4[q]; wr[4*q]=v.x; wr[4*q+1]=v.y; wr[4*q+2]=v.z; wr[4*q+3]=v.w; }
  float bias=b1[g]+b2[g];
  float xr[16];
  #pragma unroll
  for(int r=0;r<16;r++) xr[r]=x[(size_t)(m0+r)*64+l];
  #pragma unroll
  for(int r=0;r<16;r++){
    float a0=bias,a1=0.f,a2=0.f,a3=0.f;
    #pragma unroll
    for(int q=0;q<16;q++){
      a0=fmaf(wr[4*q+0],rdl(xr[r],4*q+0),a0);
      a1=fmaf(wr[4*q+1],rdl(xr[r],4*q+1),a1);
      a2=fmaf(wr[4*q+2],rdl(xr[r],4*q+2),a2);
      a3=fmaf(wr[4*q+3],rdl(xr[r],4*q+3),a3);
    }
    out[(size_t)(m0+r)*256+g]=(a0+a1)+(a2+a3);
  }
}

// ---------------- BiLSTM: 128 blocks = 64 batch x 2 dir; per-wave h/c copies, 1 barrier/step
__global__ __launch_bounds__(256,1) void lstm_seq(const float* __restrict__ xg_f,
                                                  const float* __restrict__ xg_b,
                                                  const float* __restrict__ Whh_f,
                                                  const float* __restrict__ Whh_b,
                                                  float* __restrict__ hf,
                                                  float* __restrict__ hb){
  int tid=threadIdx.x, l=tid&63, w=tid>>6;
  int dir=blockIdx.x>>6, b=blockIdx.x&63;
  const float* xg = dir? xg_b : xg_f;
  const float* Whh= dir? Whh_b: Whh_f;
  float* out = dir? hb : hf;
  float wr[64];
  const float4* W4=(const float4*)(Whh+(size_t)(w*64+l)*64);
  #pragma unroll
  for(int q=0;q<16;q++){ float4 v=W4[q]; wr[4*q]=v.x; wr[4*q+1]=v.y; wr[4*q+2]=v.z; wr[4*q+3]=v.w; }
  __shared__ float z_s[2][256];
  float h=0.f, c=0.f;
  const int tstart = dir?(NKn-1):0, dt = dir?-1:1;
  const float* xgb = xg + (size_t)b*NKn*256 + w*64 + l;
  float xv = xgb[(size_t)tstart*256];
  for(int s=0;s<NKn;s++){
    int t=tstart+s*dt;
    float xnx=0.f;
    if (s<NKn-1) xnx = xgb[(size_t)(t+dt)*256];     // prefetch next step's xg
    float a0=xv,a1=0.f,a2=0.f,a3=0.f;
    #pragma unroll
    for(int q=0;q<16;q++){
      a0=fmaf(wr[4*q+0],rdl(h,4*q+0),a0);
      a1=fmaf(wr[4*q+1],rdl(h,4*q+1),a1);
      a2=fmaf(wr[4*q+2],rdl(h,4*q+2),a2);
      a3=fmaf(wr[4*q+3],rdl(h,4*q+3),a3);
    }
    z_s[s&1][tid]=(a0+a1)+(a2+a3);
    __syncthreads();                                 // double-buffered z -> only barrier
    float zi=z_s[s&1][l], zf=z_s[s&1][64+l], zg=z_s[s&1][128+l], zo=z_s[s&1][192+l];
    c = sigm_f(zf)*c + sigm_f(zi)*tanh_f(zg);        // redundant per wave, keeps h in regs
    h = sigm_f(zo)*tanh_f(c);
    if(w==0) out[((size_t)b*NKn+t)*64+l]=h;
    xv=xnx;
  }
}

// ---------------- sup_emb = hf + hb + sup_enc; sn = ||sup_emb|| ----------------
__global__ __launch_bounds__(256) void combine(const float* __restrict__ hf,
                                               const float* __restrict__ hb,
                                               const float* __restrict__ sup_enc,
                                               float* __restrict__ semb,
                                               float* __restrict__ sn){
  int lane = threadIdx.x&63; int wv = threadIdx.x>>6;
  size_t m = (size_t)blockIdx.x*4+wv;
  float v = hf[m*64+lane] + hb[m*64+lane] + sup_enc[m*64+lane];
  semb[m*64+lane]=v;
  float s=v*v;
  #pragma unroll
  for (int o=32;o>0;o>>=1) s += __shfl_xor(s,o,64);
  if (lane==0) sn[m]=sqrtf(s);
}

// ---------------- cell: h_used=h+r; z=zx+Whh.hu; gates; h_next=h2+x  (16 rows/block) -------
__global__ __launch_bounds__(256,1) void cell_step(const float* __restrict__ h_in,
                                                   const float* __restrict__ r_in,
                                                   const float* __restrict__ zx,
                                                   const float* __restrict__ Whh,
                                                   const float* __restrict__ x,
                                                   float* __restrict__ c_io,
                                                   float* __restrict__ h_used,
                                                   float* __restrict__ h_next){
  int tid=threadIdx.x, l=tid&63, w=tid>>6;
  int m0=blockIdx.x*16;
  float wr[64];
  const float4* W4=(const float4*)(Whh+(size_t)(w*64+l)*64);
  #pragma unroll
  for(int q=0;q<16;q++){ float4 v=W4[q]; wr[4*q]=v.x; wr[4*q+1]=v.y; wr[4*q+2]=v.z; wr[4*q+3]=v.w; }
  float hur[16];
  #pragma unroll
  for(int r=0;r<16;r++) hur[r]=h_in[(size_t)(m0+r)*64+l]+r_in[(size_t)(m0+r)*64+l];
  if(w==0){
    #pragma unroll
    for(int r=0;r<16;r++) h_used[(size_t)(m0+r)*64+l]=hur[r];
  }
  __shared__ float z_s[16*256];
  #pragma unroll
  for(int r=0;r<16;r++){
    float a0=zx[(size_t)(m0+r)*256+w*64+l],a1=0.f,a2=0.f,a3=0.f;
    #pragma unroll
    for(int q=0;q<16;q++){
      a0=fmaf(wr[4*q+0],rdl(hur[r],4*q+0),a0);
      a1=fmaf(wr[4*q+1],rdl(hur[r],4*q+1),a1);
      a2=fmaf(wr[4*q+2],rdl(hur[r],4*q+2),a2);
      a3=fmaf(wr[4*q+3],rdl(hur[r],4*q+3),a3);
    }
    z_s[r*256+tid]=(a0+a1)+(a2+a3);
  }
  __syncthreads();
  #pragma unroll
  for(int q=0;q<4;q++){
    int r=q*4+w; size_t m=(size_t)(m0+r);
    float zi=z_s[r*256+l], zf=z_s[r*256+64+l], zg=z_s[r*256+128+l], zo=z_s[r*256+192+l];
    float c=sigm_f(zf)*c_io[m*64+l]+sigm_f(zi)*tanh_f(zg);
    c_io[m*64+l]=c;
    h_next[m*64+l]=sigm_f(zo)*tanh_f(c)+x[m*64+l];
  }
}

// ---------------- attention: scores -> softmax -> r   (16 targets/block, 64x8 blocks) ------
__global__ __launch_bounds__(256,1) void attn_step(const float* __restrict__ h_used,
                                                   const float* __restrict__ semb,
                                                   float* __restrict__ r_out){
  int tid=threadIdx.x, l=tid&63, w=tid>>6;
  int b=blockIdx.x>>3, t0=(blockIdx.x&7)*16;
  int j=w*64+l; bool valid=j<NKn;
  __shared__ __attribute__((aligned(16))) float ss[NKn*64];     // 51.2 KB semb tile
  __shared__ __attribute__((aligned(16))) float att_s[NKn*20];  // 16 KB, stride 20 (conflict-free b128)
  __shared__ float wredA[64], wredB[64];
  { // stage semb tile for the r-phase (column reads are 2-way/free)
    const float4* src=(const float4*)(semb+(size_t)b*NKn*64);
    float4* dst=(float4*)ss;
    for(int i=tid;i<NKn*16;i+=256) dst[i]=src[i];
  }
  float hreg[16];
  #pragma unroll
  for(int t=0;t<16;t++) hreg[t]=h_used[((size_t)(b*Tn+t0+t))*64+l];
  float4 s4[16];
  if(valid){
    const float4* sp=(const float4*)(semb+((size_t)b*NKn+j)*64);
    #pragma unroll
    for(int q=0;q<16;q++) s4[q]=sp[q];
  } else {
    #pragma unroll
    for(int q=0;q<16;q++) s4[q]=make_float4(0.f,0.f,0.f,0.f);
  }
  // scores: lane j holds semb row; broadcast h via readlane
  float scr[16];
  #pragma unroll
  for(int t=0;t<16;t++){
    float a0=0.f,a1=0.f,a2=0.f,a3=0.f;
    #pragma unroll
    for(int q=0;q<16;q++){
      a0=fmaf(s4[q].x,rdl(hreg[t],4*q+0),a0);
      a1=fmaf(s4[q].y,rdl(hreg[t],4*q+1),a1);
      a2=fmaf(s4[q].z,rdl(hreg[t],4*q+2),a2);
      a3=fmaf(s4[q].w,rdl(hreg[t],4*q+3),a3);
    }
    scr[t]=(a0+a1)+(a2+a3);
  }
  // softmax over j (cross-wave via tiny LDS exchange)
  float mx[16];
  #pragma unroll
  for(int t=0;t<16;t++){
    float m = valid ? scr[t] : -1e30f;
    #pragma unroll
    for(int o=32;o>0;o>>=1) m=fmaxf(m,__shfl_xor(m,o,64));
    mx[t]=m;
  }
  if(l==0){
    #pragma unroll
    for(int t=0;t<16;t++) wredA[t*4+w]=mx[t];
  }
  __syncthreads();
  float ex[16];
  #pragma unroll
  for(int t=0;t<16;t++){
    const float4 m4=*(const float4*)&wredA[t*4];
    float gm=fmaxf(fmaxf(m4.x,m4.y),fmaxf(m4.z,m4.w));
    float e=valid?__expf(scr[t]-gm):0.f;
    ex[t]=e;
    float s=e;
    #pragma unroll
    for(int o=32;o>0;o>>=1) s+=__shfl_xor(s,o,64);
    mx[t]=s;                       // reuse as wave-partial sum
  }
  if(l==0){
    #pragma unroll
    for(int t=0;t<16;t++) wredB[t*4+w]=mx[t];
  }
  __syncthreads();
  #pragma unroll
  for(int t=0;t<16;t++){
    const float4 s4v=*(const float4*)&wredB[t*4];
    float tot=(s4v.x+s4v.y)+(s4v.z+s4v.w);
    ex[t]*=1.0f/tot;               // ex[] is now att
  }
  if(valid){
    #pragma unroll
    for(int cg=0;cg<4;cg++){
      float4 a4=make_float4(ex[4*cg+0],ex[4*cg+1],ex[4*cg+2],ex[4*cg+3]);
      *(float4*)&att_s[j*20+4*cg]=a4;
    }
  }
  __syncthreads();
  // r-phase: wave w owns targets w*4..w*4+3; lane = e; broadcast att via readlane
  float4 areg[4];
  #pragma unroll
  for(int c=0;c<4;c++){
    int jj=c*64+l;
    areg[c]=(jj<NKn)? *(const float4*)&att_s[jj*20+w*4] : make_float4(0.f,0.f,0.f,0.f);
  }
  float r0=0.f,r1=0.f,r2=0.f,r3=0.f;
  #pragma unroll
  for(int c=0;c<4;c++){
    const int lim=(c<3)?64:(NKn-192);
    #pragma unroll 16
    for(int jl=0;jl<lim;jl++){
      float sv=ss[(c*64+jl)*64+l];
      r0=fmaf(rdl(areg[c].x,jl),sv,r0);
      r1=fmaf(rdl(areg[c].y,jl),sv,r1);
      r2=fmaf(rdl(areg[c].z,jl),sv,r2);
      r3=fmaf(rdl(areg[c].w,jl),sv,r3);
    }
  }
  {
    size_t m=(size_t)(b*Tn+t0+w*4);
    r_out[(m+0)*64+l]=r0;
    r_out[(m+1)*64+l]=r1;
    r_out[(m+2)*64+l]=r2;
    r_out[(m+3)*64+l]=r3;
  }
}

// ---------------- final cosine-sim softmax -> d_out (norms folded in) ----------------
__global__ __launch_bounds__(256,1) void final_attn(const float* __restrict__ h_fin,
                                                    const float* __restrict__ semb,
                                                    const float* __restrict__ sn,
                                                    float* __restrict__ out){
  int tid=threadIdx.x, l=tid&63, w=tid>>6;
  int b=blockIdx.x>>3, t0=(blockIdx.x&7)*16;
  int j=w*64+l; bool valid=j<NKn;
  __shared__ float wredA[64], wredB[64];
  float hreg[16];
  #pragma unroll
  for(int t=0;t<16;t++) hreg[t]=h_fin[((size_t)(b*Tn+t0+t))*64+l];
  float tnorm[16];
  #pragma unroll
  for(int t=0;t<16;t++){
    float s=hreg[t]*hreg[t];
    #pragma unroll
    for(int o=32;o>0;o>>=1) s+=__shfl_xor(s,o,64);
    tnorm[t]=sqrtf(s);
  }
  float snj = valid ? sn[(size_t)b*NKn+j] : 1.f;
  float4 s4[16];
  if(valid){
    const float4* sp=(const float4*)(semb+((size_t)b*NKn+j)*64);
    #pragma unroll
    for(int q=0;q<16;q++) s4[q]=sp[q];
  } else {
    #pragma unroll
    for(int q=0;q<16;q++) s4[q]=make_float4(0.f,0.f,0.f,0.f);
  }
  float scr[16];
  #pragma unroll
  for(int t=0;t<16;t++){
    float a0=0.f,a1=0.f,a2=0.f,a3=0.f;
    #pragma unroll
    for(int q=0;q<16;q++){
      a0=fmaf(s4[q].x,rdl(hreg[t],4*q+0),a0);
      a1=fmaf(s4[q].y,rdl(hreg[t],4*q+1),a1);
      a2=fmaf(s4[q].z,rdl(hreg[t],4*q+2),a2);
      a3=fmaf(s4[q].w,rdl(hreg[t],4*q+3),a3);
    }
    scr[t]=((a0+a1)+(a2+a3)) / fmaxf(tnorm[t]*snj,1e-8f);
  }
  float mx[16];
  #pragma unroll
  for(int t=0;t<16;t++){
    float m = valid ? scr[t] : -1e30f;
    #pragma unroll
    for(int o=32;o>0;o>>=1) m=fmaxf(m,__shfl_xor(m,o,64));
    mx[t]=m;
  }
  if(l==0){
    #pragma unroll
    for(int t=0;t<16;t++) wredA[t*4+w]=mx[t];
  }
  __syncthreads();
  float ex[16];
  #pragma unroll
  for(int t=0;t<16;t++){
    const float4 m4=*(const float4*)&wredA[t*4];
    float gm=fmaxf(fmaxf(m4.x,m4.y),fmaxf(m4.z,m4.w));
    float e=valid?__expf(scr[t]-gm):0.f;
    ex[t]=e;
    float s=e;
    #pragma unroll
    for(int o=32;o>0;o>>=1) s+=__shfl_xor(s,o,64);
    mx[t]=s;
  }
  if(l==0){
    #pragma unroll
    for(int t=0;t<16;t++) wredB[t*4+w]=mx[t];
  }
  __syncthreads();
  #pragma unroll
  for(int t=0;t<16;t++){
    const float4 s4v=*(const float4*)&wredB[t*4];
    float tot=(s4v.x+s4v.y)+(s4v.z+s4v.w);
    if(valid) out[((size_t)(b*Tn+t0+t))*NKn + j]=ex[t]*(1.0f/tot);
  }
}

extern "C" void kernel_launch(void* const* d_in, const int* in_sizes, int n_in,
                              void* d_out, int out_size, void* d_ws, size_t ws_size,
                              hipStream_t stream) {
  (void)in_sizes; (void)n_in; (void)out_size; (void)ws_size;
  const int*   sup_toks = (const int*)d_in[0];
  const int*   tgt_toks = (const int*)d_in[1];
  const float* emb      = (const float*)d_in[2];
  const float* f_Wih    = (const float*)d_in[3];
  const float* f_Whh    = (const float*)d_in[4];
  const float* f_bih    = (const float*)d_in[5];
  const float* f_bhh    = (const float*)d_in[6];
  const float* gf_Wih   = (const float*)d_in[7];
  const float* gf_Whh   = (const float*)d_in[8];
  const float* gf_bih   = (const float*)d_in[9];
  const float* gf_bhh   = (const float*)d_in[10];
  const float* gb_Wih   = (const float*)d_in[11];
  const float* gb_Whh   = (const float*)d_in[12];
  const float* gb_bih   = (const float*)d_in[13];
  const float* gb_bhh   = (const float*)d_in[14];

  float* ws = (float*)d_ws;
  float* sup_enc = ws;                         // 819200
  float* tgt_enc = sup_enc + 819200;           // 524288
  float* bufA    = tgt_enc + 524288;           // 3276800 : xg_f, later zx
  float* bufB    = bufA    + 3276800;          // 3276800 : xg_b, later h0/h1/c/r/h_used
  float* semb    = bufB    + 3276800;          // 819200  : hf, then sup_emb
  float* hb      = semb    + 819200;           // 819200
  float* sn      = hb      + 819200;           // 12800

  float* xg_f = bufA;
  float* xg_b = bufB;

  // phase A: embedding sums
  embed_sum<<<800,256,0,stream>>>(sup_toks, emb, sup_enc);   // 12800 rows
  embed_sum<<<512,256,0,stream>>>(tgt_toks, emb, tgt_enc);   // 8192 rows

  // phase B: BiLSTM
  gemm_xw<<<800,256,0,stream>>>(sup_enc, gf_Wih, gf_bih, gf_bhh, xg_f);
  gemm_xw<<<800,256,0,stream>>>(sup_enc, gb_Wih, gb_bih, gb_bhh, xg_b);
  lstm_seq<<<128,256,0,stream>>>(xg_f, xg_b, gf_Whh, gb_Whh, semb /*hf*/, hb);
  combine<<<3200,256,0,stream>>>(semb, hb, sup_enc, semb, sn);

  // phase C: K=5 attention-LSTM iterations (bufA,bufB now dead -> reuse)
  float* zx     = bufA;                 // 2097152
  float* h0     = bufB;                 // 524288
  float* h1     = h0 + 524288;
  float* cbuf   = h1 + 524288;
  float* rbuf   = cbuf + 524288;
  float* h_used = rbuf + 524288;

  gemm_xw<<<512,256,0,stream>>>(tgt_enc, f_Wih, f_bih, f_bhh, zx);
  hipMemsetAsync(h0, 0, (size_t)4*524288*sizeof(float), stream);  // h0,h1,c,r = 0

  for (int k=0;k<5;k++){
    float* hin  = (k&1)? h1 : h0;
    float* hout = (k&1)? h0 : h1;
    cell_step<<<512,256,0,stream>>>(hin, rbuf, zx, f_Whh, tgt_enc, cbuf, h_used, hout);
    if (k<4) attn_step<<<512,256,0,stream>>>(h_used, semb, rbuf);
  }
  // final h is h1 (k=4: hin=h0 -> hout=h1)
  final_attn<<<512,256,0,stream>>>(h1, semb, sn, (float*)d_out);
}

// Round 3
// 488.749 us; speedup vs baseline: 1.1362x; 1.0273x over previous
//
#include <hip/hip_runtime.h>

#define Bn   64
#define Tn   128
#define NKn  200
#define En   64
#define Ln   40

__device__ __forceinline__ float sigm_f(float x){ return 1.0f/(1.0f+__expf(-x)); }
__device__ __forceinline__ float tanh_f(float x){ float e=__expf(2.0f*x); return 1.0f-2.0f/(e+1.0f); }
__device__ __forceinline__ float rdl(float v, int ln){
  return __uint_as_float(__builtin_amdgcn_readlane(__float_as_uint(v), (unsigned)ln));
}
// barrier that does NOT drain vmcnt: global prefetches stay in flight (m139 pattern)
#define BAR_LGKM() asm volatile("s_waitcnt lgkmcnt(0)\n\ts_barrier" ::: "memory")

// ---------------- both embedding gather-sums in one grid ----------------
__global__ __launch_bounds__(256) void embed_all(const int* __restrict__ sup,
                                                 const int* __restrict__ tgt,
                                                 const float* __restrict__ emb,
                                                 float* __restrict__ sup_enc,
                                                 float* __restrict__ tgt_enc){
  int tid = threadIdx.x;
  int gr  = blockIdx.x*16 + (tid>>4);
  int e4  = tid & 15;
  const int* tr; float* out;
  if (gr < 12800){ tr = sup + (size_t)gr*Ln;        out = sup_enc + (size_t)gr*64; }
  else           { int r2=gr-12800; tr = tgt + (size_t)r2*Ln; out = tgt_enc + (size_t)r2*64; }
  float4 acc = {0.f,0.f,0.f,0.f};
  #pragma unroll 4
  for (int t=0;t<Ln;t++){
    int tok = tr[t];
    float4 v = ((const float4*)emb)[(size_t)tok*16 + e4];
    acc.x+=v.x; acc.y+=v.y; acc.z+=v.z; acc.w+=v.w;
  }
  ((float4*)out)[e4] = acc;
}

// ---------------- both support GEMMs (gf + gb) in one grid ----------------
__global__ __launch_bounds__(256,2) void gemm_sup(const float* __restrict__ x,
                                                  const float* __restrict__ Wa, const float* __restrict__ Wb,
                                                  const float* __restrict__ ba1,const float* __restrict__ ba2,
                                                  const float* __restrict__ bb1,const float* __restrict__ bb2,
                                                  float* __restrict__ outa, float* __restrict__ outb){
  int tid=threadIdx.x, l=tid&63, w=tid>>6;
  int g = w*64+l;
  int blk = blockIdx.x;
  bool second = blk>=800;
  const float* W  = second? Wb : Wa;
  const float* b1 = second? bb1: ba1;
  const float* b2 = second? bb2: ba2;
  float* out      = second? outb: outa;
  int m0 = (second? blk-800 : blk)*16;
  float wr[64];
  const float4* W4=(const float4*)(W + (size_t)g*64);
  #pragma unroll
  for(int q=0;q<16;q++){ float4 v=W4[q]; wr[4*q]=v.x; wr[4*q+1]=v.y; wr[4*q+2]=v.z; wr[4*q+3]=v.w; }
  float bias=b1[g]+b2[g];
  float xr[16];
  #pragma unroll
  for(int r=0;r<16;r++) xr[r]=x[(size_t)(m0+r)*64+l];
  #pragma unroll
  for(int r=0;r<16;r++){
    float a0=bias,a1=0.f,a2=0.f,a3=0.f;
    #pragma unroll
    for(int q=0;q<16;q++){
      a0=fmaf(wr[4*q+0],rdl(xr[r],4*q+0),a0);
      a1=fmaf(wr[4*q+1],rdl(xr[r],4*q+1),a1);
      a2=fmaf(wr[4*q+2],rdl(xr[r],4*q+2),a2);
      a3=fmaf(wr[4*q+3],rdl(xr[r],4*q+3),a3);
    }
    out[(size_t)(m0+r)*256+g]=(a0+a1)+(a2+a3);
  }
}

// ---------------- BiLSTM: raw lgkm barrier (no vmcnt drain), depth-2 xg prefetch ----------
__global__ __launch_bounds__(256,2) void lstm_seq(const float* __restrict__ xg_f,
                                                  const float* __restrict__ xg_b,
                                                  const float* __restrict__ Whh_f,
                                                  const float* __restrict__ Whh_b,
                                                  float* __restrict__ hf,
                                                  float* __restrict__ hb){
  int tid=threadIdx.x, l=tid&63, w=tid>>6;
  int dir=blockIdx.x>>6, b=blockIdx.x&63;
  const float* xg = dir? xg_b : xg_f;
  const float* Whh= dir? Whh_b: Whh_f;
  float* out = dir? hb : hf;
  float wr[64];
  const float4* W4=(const float4*)(Whh+(size_t)(w*64+l)*64);
  #pragma unroll
  for(int q=0;q<16;q++){ float4 v=W4[q]; wr[4*q]=v.x; wr[4*q+1]=v.y; wr[4*q+2]=v.z; wr[4*q+3]=v.w; }
  __shared__ float z_s[2][256];
  float h=0.f, c=0.f;
  const int tstart = dir?(NKn-1):0, dt = dir?-1:1;
  const float* xgb = xg + (size_t)b*NKn*256 + w*64 + l;
  float xv0 = xgb[(size_t)tstart*256];
  float xv1 = xgb[(size_t)(tstart+dt)*256];
  for(int s=0;s<NKn;s++){
    int t=tstart+s*dt;
    float xnx=0.f;
    if (s+2<NKn) xnx = xgb[(size_t)(t+2*dt)*256];     // depth-2 prefetch, survives barrier
    float a0=xv0,a1=0.f,a2=0.f,a3=0.f;
    #pragma unroll
    for(int q=0;q<16;q++){
      a0=fmaf(wr[4*q+0],rdl(h,4*q+0),a0);
      a1=fmaf(wr[4*q+1],rdl(h,4*q+1),a1);
      a2=fmaf(wr[4*q+2],rdl(h,4*q+2),a2);
      a3=fmaf(wr[4*q+3],rdl(h,4*q+3),a3);
    }
    z_s[s&1][tid]=(a0+a1)+(a2+a3);
    BAR_LGKM();                                        // lgkm-only barrier
    float zi=z_s[s&1][l], zf=z_s[s&1][64+l], zg=z_s[s&1][128+l], zo=z_s[s&1][192+l];
    c = sigm_f(zf)*c + sigm_f(zi)*tanh_f(zg);          // redundant per wave, h stays in regs
    h = sigm_f(zo)*tanh_f(c);
    if(w==0) out[((size_t)b*NKn+t)*64+l]=h;
    xv0=xv1; xv1=xnx;
  }
}

// ---------------- zx GEMM (blocks 0..511) + combine/norms (blocks 512..1311) --------------
__global__ __launch_bounds__(256,2) void gemmz_combine(const float* __restrict__ tgt_enc,
                                                       const float* __restrict__ W,
                                                       const float* __restrict__ b1,
                                                       const float* __restrict__ b2,
                                                       float* __restrict__ zx,
                                                       const float* __restrict__ hf,
                                                       const float* __restrict__ hb,
                                                       const float* __restrict__ sup_enc,
                                                       float* __restrict__ semb,
                                                       float* __restrict__ sn){
  int tid=threadIdx.x, l=tid&63, w=tid>>6;
  int blk=blockIdx.x;
  if (blk < 512){
    int g=w*64+l, m0=blk*16;
    float wr[64];
    const float4* W4=(const float4*)(W + (size_t)g*64);
    #pragma unroll
    for(int q=0;q<16;q++){ float4 v=W4[q]; wr[4*q]=v.x; wr[4*q+1]=v.y; wr[4*q+2]=v.z; wr[4*q+3]=v.w; }
    float bias=b1[g]+b2[g];
    float xr[16];
    #pragma unroll
    for(int r=0;r<16;r++) xr[r]=tgt_enc[(size_t)(m0+r)*64+l];
    #pragma unroll
    for(int r=0;r<16;r++){
      float a0=bias,a1=0.f,a2=0.f,a3=0.f;
      #pragma unroll
      for(int q=0;q<16;q++){
        a0=fmaf(wr[4*q+0],rdl(xr[r],4*q+0),a0);
        a1=fmaf(wr[4*q+1],rdl(xr[r],4*q+1),a1);
        a2=fmaf(wr[4*q+2],rdl(xr[r],4*q+2),a2);
        a3=fmaf(wr[4*q+3],rdl(xr[r],4*q+3),a3);
      }
      zx[(size_t)(m0+r)*256+g]=(a0+a1)+(a2+a3);
    }
  } else {
    int m0=(blk-512)*16;
    #pragma unroll
    for(int q=0;q<4;q++){
      size_t m=(size_t)m0 + w*4 + q;
      float v = hf[m*64+l] + hb[m*64+l] + sup_enc[m*64+l];
      semb[m*64+l]=v;
      float s=v*v;
      #pragma unroll
      for (int o=32;o>0;o>>=1) s += __shfl_xor(s,o,64);
      if (l==0) sn[m]=sqrtf(s);
    }
  }
}

// ---------------- fused LSTM-cell + attention (one K iteration), 512 blocks ----------------
__global__ __launch_bounds__(256,2) void fused_cell_attn(const float* __restrict__ h_in,
                                                         const float* __restrict__ zx,
                                                         const float* __restrict__ Whh,
                                                         const float* __restrict__ x,
                                                         float* __restrict__ c_io,
                                                         float* __restrict__ r_io,
                                                         const float* __restrict__ semb,
                                                         float* __restrict__ h_next,
                                                         int zero){
  int tid=threadIdx.x, l=tid&63, w=tid>>6;
  int b=blockIdx.x>>3, t0=(blockIdx.x&7)*16;
  int m0=b*Tn+t0;
  int g=tid;                      // gate index AND support-row index j
  __shared__ float sbuf[4096];    // z (16x256), then att (200x20)
  __shared__ float wredA[64], wredB[64];
  float wr[64];
  const float4* W4=(const float4*)(Whh+(size_t)g*64);
  #pragma unroll
  for(int q=0;q<16;q++){ float4 v=W4[q]; wr[4*q]=v.x; wr[4*q+1]=v.y; wr[4*q+2]=v.z; wr[4*q+3]=v.w; }
  float hur[16];
  #pragma unroll
  for(int r=0;r<16;r++) hur[r] = zero? 0.f : (h_in[(size_t)(m0+r)*64+l]+r_io[(size_t)(m0+r)*64+l]);
  // ---- cell GEMV ----
  #pragma unroll
  for(int r=0;r<16;r++){
    float a0=zx[(size_t)(m0+r)*256+g],a1=0.f,a2=0.f,a3=0.f;
    #pragma unroll
    for(int q=0;q<16;q++){
      a0=fmaf(wr[4*q+0],rdl(hur[r],4*q+0),a0);
      a1=fmaf(wr[4*q+1],rdl(hur[r],4*q+1),a1);
      a2=fmaf(wr[4*q+2],rdl(hur[r],4*q+2),a2);
      a3=fmaf(wr[4*q+3],rdl(hur[r],4*q+3),a3);
    }
    sbuf[r*256+tid]=(a0+a1)+(a2+a3);
  }
  __syncthreads();
  #pragma unroll
  for(int q=0;q<4;q++){
    int r=q*4+w; size_t m=(size_t)(m0+r);
    float zi=sbuf[r*256+l], zf=sbuf[r*256+64+l], zg=sbuf[r*256+128+l], zo=sbuf[r*256+192+l];
    float cp = zero? 0.f : c_io[m*64+l];
    float c=sigm_f(zf)*cp+sigm_f(zi)*tanh_f(zg);
    c_io[m*64+l]=c;
    h_next[m*64+l]=sigm_f(zo)*tanh_f(c)+x[m*64+l];
  }
  // ---- attention on hur ----
  bool valid = g<NKn;
  const float* sbase = semb + (size_t)b*NKn*64;
  float4 s4[16];
  if(valid){
    const float4* sp=(const float4*)(sbase+(size_t)g*64);
    #pragma unroll
    for(int q=0;q<16;q++) s4[q]=sp[q];
  } else {
    #pragma unroll
    for(int q=0;q<16;q++) s4[q]=make_float4(0.f,0.f,0.f,0.f);
  }
  float scr[16];
  #pragma unroll
  for(int t=0;t<16;t++){
    float a0=0.f,a1=0.f,a2=0.f,a3=0.f;
    #pragma unroll
    for(int q=0;q<16;q++){
      a0=fmaf(s4[q].x,rdl(hur[t],4*q+0),a0);
      a1=fmaf(s4[q].y,rdl(hur[t],4*q+1),a1);
      a2=fmaf(s4[q].z,rdl(hur[t],4*q+2),a2);
      a3=fmaf(s4[q].w,rdl(hur[t],4*q+3),a3);
    }
    scr[t]=(a0+a1)+(a2+a3);
  }
  float mx[16];
  #pragma unroll
  for(int t=0;t<16;t++){
    float m = valid ? scr[t] : -1e30f;
    #pragma unroll
    for(int o=32;o>0;o>>=1) m=fmaxf(m,__shfl_xor(m,o,64));
    mx[t]=m;
  }
  if(l==0){
    #pragma unroll
    for(int t=0;t<16;t++) wredA[t*4+w]=mx[t];
  }
  __syncthreads();                   // also protects sbuf z-reads above vs att writes below
  float ex[16];
  #pragma unroll
  for(int t=0;t<16;t++){
    const float4 m4=*(const float4*)&wredA[t*4];
    float gm=fmaxf(fmaxf(m4.x,m4.y),fmaxf(m4.z,m4.w));
    float e=valid?__expf(scr[t]-gm):0.f;
    ex[t]=e;
    float s=e;
    #pragma unroll
    for(int o=32;o>0;o>>=1) s+=__shfl_xor(s,o,64);
    mx[t]=s;
  }
  if(l==0){
    #pragma unroll
    for(int t=0;t<16;t++) wredB[t*4+w]=mx[t];
  }
  __syncthreads();
  #pragma unroll
  for(int t=0;t<16;t++){
    const float4 s4v=*(const float4*)&wredB[t*4];
    float tot=(s4v.x+s4v.y)+(s4v.z+s4v.w);
    ex[t]*=1.0f/tot;                 // att
  }
  if(valid){
    #pragma unroll
    for(int cg=0;cg<4;cg++)
      *(float4*)&sbuf[g*20+4*cg]=make_float4(ex[4*cg+0],ex[4*cg+1],ex[4*cg+2],ex[4*cg+3]);
  }
  __syncthreads();
  float4 areg[4];
  #pragma unroll
  for(int c=0;c<4;c++){
    int jj=c*64+l;
    areg[c]=(jj<NKn)? *(const float4*)&sbuf[jj*20+w*4] : make_float4(0.f,0.f,0.f,0.f);
  }
  float r0=0.f,r1=0.f,r2=0.f,r3=0.f;
  #pragma unroll
  for(int c=0;c<4;c++){
    const int lim=(c<3)?64:(NKn-192);
    #pragma unroll 16
    for(int jl=0;jl<lim;jl++){
      float sv=sbase[(size_t)(c*64+jl)*64+l];   // L2-resident global read
      r0=fmaf(rdl(areg[c].x,jl),sv,r0);
      r1=fmaf(rdl(areg[c].y,jl),sv,r1);
      r2=fmaf(rdl(areg[c].z,jl),sv,r2);
      r3=fmaf(rdl(areg[c].w,jl),sv,r3);
    }
  }
  {
    size_t m=(size_t)(m0+w*4);
    r_io[(m+0)*64+l]=r0;
    r_io[(m+1)*64+l]=r1;
    r_io[(m+2)*64+l]=r2;
    r_io[(m+3)*64+l]=r3;
  }
}

// ---------------- fused final cell + cosine-sim softmax -> d_out ----------------
__global__ __launch_bounds__(256,2) void fused_cell_final(const float* __restrict__ h_in,
                                                          const float* __restrict__ r_in,
                                                          const float* __restrict__ zx,
                                                          const float* __restrict__ Whh,
                                                          const float* __restrict__ x,
                                                          const float* __restrict__ c_in,
                                                          const float* __restrict__ semb,
                                                          const float* __restrict__ sn,
                                                          float* __restrict__ out){
  int tid=threadIdx.x, l=tid&63, w=tid>>6;
  int b=blockIdx.x>>3, t0=(blockIdx.x&7)*16;
  int m0=b*Tn+t0;
  int g=tid;
  __shared__ float sbuf[5120];     // z (16x256) + h_fin (16x64) at offset 4096
  __shared__ float wredA[64], wredB[64];
  float wr[64];
  const float4* W4=(const float4*)(Whh+(size_t)g*64);
  #pragma unroll
  for(int q=0;q<16;q++){ float4 v=W4[q]; wr[4*q]=v.x; wr[4*q+1]=v.y; wr[4*q+2]=v.z; wr[4*q+3]=v.w; }
  float hur[16];
  #pragma unroll
  for(int r=0;r<16;r++) hur[r]=h_in[(size_t)(m0+r)*64+l]+r_in[(size_t)(m0+r)*64+l];
  #pragma unroll
  for(int r=0;r<16;r++){
    float a0=zx[(size_t)(m0+r)*256+g],a1=0.f,a2=0.f,a3=0.f;
    #pragma unroll
    for(int q=0;q<16;q++){
      a0=fmaf(wr[4*q+0],rdl(hur[r],4*q+0),a0);
      a1=fmaf(wr[4*q+1],rdl(hur[r],4*q+1),a1);
      a2=fmaf(wr[4*q+2],rdl(hur[r],4*q+2),a2);
      a3=fmaf(wr[4*q+3],rdl(hur[r],4*q+3),a3);
    }
    sbuf[r*256+tid]=(a0+a1)+(a2+a3);
  }
  __syncthreads();
  #pragma unroll
  for(int q=0;q<4;q++){
    int r=q*4+w; size_t m=(size_t)(m0+r);
    float zi=sbuf[r*256+l], zf=sbuf[r*256+64+l], zg=sbuf[r*256+128+l], zo=sbuf[r*256+192+l];
    float c=sigm_f(zf)*c_in[m*64+l]+sigm_f(zi)*tanh_f(zg);
    sbuf[4096 + r*64 + l]=sigm_f(zo)*tanh_f(c)+x[m*64+l];   // h_fin
  }
  __syncthreads();
  float hreg[16], tnorm[16];
  #pragma unroll
  for(int r=0;r<16;r++) hreg[r]=sbuf[4096+r*64+l];
  #pragma unroll
  for(int t=0;t<16;t++){
    float s=hreg[t]*hreg[t];
    #pragma unroll
    for(int o=32;o>0;o>>=1) s+=__shfl_xor(s,o,64);
    tnorm[t]=sqrtf(s);
  }
  bool valid=g<NKn;
  float snj = valid ? sn[(size_t)b*NKn+g] : 1.f;
  float4 s4[16];
  if(valid){
    const float4* sp=(const float4*)(semb+((size_t)b*NKn+g)*64);
    #pragma unroll
    for(int q=0;q<16;q++) s4[q]=sp[q];
  } else {
    #pragma unroll
    for(int q=0;q<16;q++) s4[q]=make_float4(0.f,0.f,0.f,0.f);
  }
  float scr[16];
  #pragma unroll
  for(int t=0;t<16;t++){
    float a0=0.f,a1=0.f,a2=0.f,a3=0.f;
    #pragma unroll
    for(int q=0;q<16;q++){
      a0=fmaf(s4[q].x,rdl(hreg[t],4*q+0),a0);
      a1=fmaf(s4[q].y,rdl(hreg[t],4*q+1),a1);
      a2=fmaf(s4[q].z,rdl(hreg[t],4*q+2),a2);
      a3=fmaf(s4[q].w,rdl(hreg[t],4*q+3),a3);
    }
    scr[t]=((a0+a1)+(a2+a3)) / fmaxf(tnorm[t]*snj,1e-8f);
  }
  float mx[16];
  #pragma unroll
  for(int t=0;t<16;t++){
    float m = valid ? scr[t] : -1e30f;
    #pragma unroll
    for(int o=32;o>0;o>>=1) m=fmaxf(m,__shfl_xor(m,o,64));
    mx[t]=m;
  }
  if(l==0){
    #pragma unroll
    for(int t=0;t<16;t++) wredA[t*4+w]=mx[t];
  }
  __syncthreads();
  float ex[16];
  #pragma unroll
  for(int t=0;t<16;t++){
    const float4 m4=*(const float4*)&wredA[t*4];
    float gm=fmaxf(fmaxf(m4.x,m4.y),fmaxf(m4.z,m4.w));
    float e=valid?__expf(scr[t]-gm):0.f;
    ex[t]=e;
    float s=e;
    #pragma unroll
    for(int o=32;o>0;o>>=1) s+=__shfl_xor(s,o,64);
    mx[t]=s;
  }
  if(l==0){
    #pragma unroll
    for(int t=0;t<16;t++) wredB[t*4+w]=mx[t];
  }
  __syncthreads();
  #pragma unroll
  for(int t=0;t<16;t++){
    const float4 s4v=*(const float4*)&wredB[t*4];
    float tot=(s4v.x+s4v.y)+(s4v.z+s4v.w);
    if(valid) out[((size_t)(m0+t))*NKn + g]=ex[t]*(1.0f/tot);
  }
}

extern "C" void kernel_launch(void* const* d_in, const int* in_sizes, int n_in,
                              void* d_out, int out_size, void* d_ws, size_t ws_size,
                              hipStream_t stream) {
  (void)in_sizes; (void)n_in; (void)out_size; (void)ws_size;
  const int*   sup_toks = (const int*)d_in[0];
  const int*   tgt_toks = (const int*)d_in[1];
  const float* emb      = (const float*)d_in[2];
  const float* f_Wih    = (const float*)d_in[3];
  const float* f_Whh    = (const float*)d_in[4];
  const float* f_bih    = (const float*)d_in[5];
  const float* f_bhh    = (const float*)d_in[6];
  const float* gf_Wih   = (const float*)d_in[7];
  const float* gf_Whh   = (const float*)d_in[8];
  const float* gf_bih   = (const float*)d_in[9];
  const float* gf_bhh   = (const float*)d_in[10];
  const float* gb_Wih   = (const float*)d_in[11];
  const float* gb_Whh   = (const float*)d_in[12];
  const float* gb_bih   = (const float*)d_in[13];
  const float* gb_bhh   = (const float*)d_in[14];

  float* ws = (float*)d_ws;
  float* sup_enc = ws;                         // 819200
  float* tgt_enc = sup_enc + 819200;           // 524288
  float* bufA    = tgt_enc + 524288;           // 3276800 : xg_f, later zx
  float* bufB    = bufA    + 3276800;          // 3276800 : xg_b, later hA/hB/c/r
  float* semb    = bufB    + 3276800;          // 819200  : hf, then sup_emb
  float* hb      = semb    + 819200;           // 819200
  float* sn      = hb      + 819200;           // 12800

  float* xg_f = bufA;
  float* xg_b = bufB;

  embed_all<<<1312,256,0,stream>>>(sup_toks, tgt_toks, emb, sup_enc, tgt_enc);
  gemm_sup<<<1600,256,0,stream>>>(sup_enc, gf_Wih, gb_Wih,
                                  gf_bih, gf_bhh, gb_bih, gb_bhh, xg_f, xg_b);
  lstm_seq<<<128,256,0,stream>>>(xg_f, xg_b, gf_Whh, gb_Whh, semb /*hf*/, hb);

  float* zx   = bufA;                  // xg_f dead after lstm
  float* hA   = bufB;                  // xg_b dead after lstm
  float* hB   = hA + 524288;
  float* cbuf = hB + 524288;
  float* rbuf = cbuf + 524288;

  gemmz_combine<<<1312,256,0,stream>>>(tgt_enc, f_Wih, f_bih, f_bhh, zx,
                                       semb, hb, sup_enc, semb, sn);

  // K=5: k=0 zero-init (no memset needed), k=4 fused with final softmax
  fused_cell_attn<<<512,256,0,stream>>>(hA, zx, f_Whh, tgt_enc, cbuf, rbuf, semb, hA, 1);
  fused_cell_attn<<<512,256,0,stream>>>(hA, zx, f_Whh, tgt_enc, cbuf, rbuf, semb, hB, 0);
  fused_cell_attn<<<512,256,0,stream>>>(hB, zx, f_Whh, tgt_enc, cbuf, rbuf, semb, hA, 0);
  fused_cell_attn<<<512,256,0,stream>>>(hA, zx, f_Whh, tgt_enc, cbuf, rbuf, semb, hB, 0);
  fused_cell_final<<<512,256,0,stream>>>(hB, rbuf, zx, f_Whh, tgt_enc, cbuf, semb, sn, (float*)d_out);
}